// Round 11
// baseline (754.619 us; speedup 1.0000x reference)
//
#include <hip/hip_runtime.h>
#include <math.h>

// Problem constants
#define B_  8
#define D_  1024
#define T_  2048
#define CD_ 256
#define CS_ 8192
#define N_  (B_*T_)

#define NSPLIT 8
#define CODES_PER_SPLIT (CS_/NSPLIT)   // 1024
#define DELTA 1.5f                     // score-units; >> 2*bf16 err + tilemax storage err
#define NTILE 128                      // 64-code tiles per row (CS_/64)

// scan geometry: 4 waves * 64 rows = 256 rows/block; 64-code LDS tiles
#define ROWS_PER_WAVE 64
#define SCAN_ROWS 256
#define TILE_CODES 64

// ws layout (float offsets). Total ~18.45 MB (<= proven 18.6 MB footprint).
#define WS_ZEN   0                        // bf16 [N][256]  (2,097,152 float slots)
#define WS_CBB   2097152                  // bf16 [CS][256] (1,048,576)
#define WS_WINT  (WS_CBB + 1048576)       // f32 [D][CD]
#define WS_WOB   (WS_WINT + D_*CD_)       // bf16 [D][CD] (131,072 float slots)
#define WS_C2    (WS_WOB + D_*CD_/2)      // f32 [CS]
#define WS_TMAX  (WS_C2 + CS_)            // bf16 [N][128] (1,048,576 float slots)
#define WS_IDX   (WS_TMAX + N_*NTILE/2)   // int [N]

// d_out layout (floats): z_q, indices(as float), z_e
#define OUT_ZQ  0
#define OUT_IDX (B_*D_*T_)
#define OUT_ZE  (OUT_IDX + B_*T_)

using short8v = __attribute__((ext_vector_type(8))) short;
using float4v = __attribute__((ext_vector_type(4))) float;

__device__ __forceinline__ float wave_sum64(float v) {
#pragma unroll
  for (int off = 32; off >= 1; off >>= 1) v += __shfl_xor(v, off);
  return v;
}

__device__ __forceinline__ unsigned short f2bf_rne(float f) {
  unsigned int u = __float_as_uint(f);
  u += 0x7fffu + ((u >> 16) & 1u);
  return (unsigned short)(u >> 16);
}

__device__ __forceinline__ float bf2f(unsigned short u) {
  return __uint_as_float(((unsigned)u) << 16);
}

__device__ __forceinline__ void gload_lds16(const void* g, void* l) {
  __builtin_amdgcn_global_load_lds(
      (const __attribute__((address_space(1))) void*)g,
      (__attribute__((address_space(3))) void*)l, 16, 0, 0);
}

// ---- fused prep: one kernel, block-range dispatch ----
// [0,256): w_inT  [256,1280): wob  [1280,3328): c2  [3328,4352): cbb
__global__ __launch_bounds__(256) void prep_all(
    const float* __restrict__ in_v, const float* __restrict__ in_g,
    const float* __restrict__ out_v, const float* __restrict__ out_g,
    const float* __restrict__ cb,
    float* __restrict__ w_inT, unsigned short* __restrict__ wob,
    float* __restrict__ c2, unsigned short* __restrict__ cbb) {
  __shared__ float sh[4];
  int blk = blockIdx.x, tid = threadIdx.x;
  if (blk < CD_) {
    int c = blk;
    float v[4]; float s = 0.f;
#pragma unroll
    for (int i = 0; i < 4; ++i) {
      v[i] = in_v[c * D_ + tid + 256 * i];
      s = fmaf(v[i], v[i], s);
    }
    s = wave_sum64(s);
    if ((tid & 63) == 0) sh[tid >> 6] = s;
    __syncthreads();
    float tot = sh[0] + sh[1] + sh[2] + sh[3];
    float scale = in_g[c] / sqrtf(tot);
#pragma unroll
    for (int i = 0; i < 4; ++i)
      w_inT[(tid + 256 * i) * CD_ + c] = v[i] * scale;
  } else if (blk < CD_ + D_) {
    int d = blk - CD_;
    float v = out_v[d * CD_ + tid];
    float s = wave_sum64(v * v);
    if ((tid & 63) == 0) sh[tid >> 6] = s;
    __syncthreads();
    float tot = sh[0] + sh[1] + sh[2] + sh[3];
    float scale = out_g[d] / sqrtf(tot);
    wob[d * CD_ + tid] = f2bf_rne(v * scale);
  } else if (blk < CD_ + D_ + CS_ / 4) {
    int w = tid >> 6, lane = tid & 63;
    int s = (blk - CD_ - D_) * 4 + w;
    float acc = 0.f;
#pragma unroll
    for (int i = 0; i < 4; ++i) {
      float v = cb[(size_t)s * CD_ + lane + 64 * i];
      acc = fmaf(v, v, acc);
    }
    acc = wave_sum64(acc);
    if (lane == 0) c2[s] = acc;
  } else {
    size_t i = (size_t)(blk - CD_ - D_ - CS_ / 4) * 256 + tid;  // octet index
    float4 v0 = *(const float4*)&cb[i * 8];
    float4 v1 = *(const float4*)&cb[i * 8 + 4];
    float f[8] = {v0.x, v0.y, v0.z, v0.w, v1.x, v1.y, v1.z, v1.w};
    unsigned short us[8];
#pragma unroll
    for (int m = 0; m < 8; ++m) us[m] = f2bf_rne(f[m]);
    *(uint4*)&cbb[i * 8] = *(uint4*)&us[0];
  }
}

// ---- K1: z_e = w_in @ z + b, fused transpose+bf16 (zeN) epilogue ----
// R8 geometry (proven 140us): tile 64c x 128t, TK=32, 256 thr, 8c x 4t
// microtile, 2 blocks/CU. Double-buffered global_load_lds staging.
// Per-output K-order = sequential kk (bit-identical z_e across rounds).
__global__ __launch_bounds__(256) void ze_gemm(
    const float* __restrict__ z, const float* __restrict__ w_inT,
    const float* __restrict__ in_b, float* __restrict__ out,
    unsigned short* __restrict__ zeN) {
  __shared__ __align__(16) float At[2][32 * 64];    // 8 KB each
  __shared__ __align__(16) float Bt[2][32 * 128];   // 16 KB each
  int tid = threadIdx.x, tx = tid & 31, ty = tid >> 5;
  int w = tid >> 6, l = tid & 63;
  int t0 = blockIdx.x * 128, c0 = blockIdx.y * 64, b = blockIdx.z;
  const float* zb = z + (size_t)b * D_ * T_;

  auto stage = [&](int buf, int kc) {
#pragma unroll
    for (int i = 0; i < 2; ++i) {
      int g = w * 2 + i;
      int kk = g * 4 + (l >> 4);
      int c = (l & 15) * 4;
      gload_lds16(&w_inT[(size_t)(kc + kk) * CD_ + c0 + c], &At[buf][g * 256]);
    }
#pragma unroll
    for (int i = 0; i < 4; ++i) {
      int g = w * 4 + i;
      int kk = g * 2 + (l >> 5);
      int t = (l & 31) * 4;
      gload_lds16(&zb[(size_t)(kc + kk) * T_ + t0 + t], &Bt[buf][g * 256]);
    }
  };

  float acc[8][4] = {};
  stage(0, 0);
  __syncthreads();
  int cur = 0;
  for (int kt = 0; kt < D_ / 32; ++kt) {
    if (kt + 1 < D_ / 32) stage(cur ^ 1, (kt + 1) * 32);
#pragma unroll 8
    for (int kk = 0; kk < 32; ++kk) {
      float a[8], bv[4];
      *(float4*)&a[0] = *(const float4*)&At[cur][kk * 64 + ty * 8];
      *(float4*)&a[4] = *(const float4*)&At[cur][kk * 64 + ty * 8 + 4];
      *(float4*)&bv[0] = *(const float4*)&Bt[cur][kk * 128 + tx * 4];
#pragma unroll
      for (int j = 0; j < 8; ++j)
#pragma unroll
        for (int m = 0; m < 4; ++m)
          acc[j][m] = fmaf(a[j], bv[m], acc[j][m]);
    }
    __syncthreads();
    cur ^= 1;
  }

  float bias[8];
#pragma unroll
  for (int j = 0; j < 8; ++j) bias[j] = in_b[c0 + ty * 8 + j];

  // z_e fp32: [b][c][t]
#pragma unroll
  for (int j = 0; j < 8; ++j) {
    int c = c0 + ty * 8 + j;
    float4 o;
    o.x = acc[j][0] + bias[j]; o.y = acc[j][1] + bias[j];
    o.z = acc[j][2] + bias[j]; o.w = acc[j][3] + bias[j];
    *(float4*)&out[OUT_ZE + (size_t)(b * CD_ + c) * T_ + t0 + tx * 4] = o;
  }
  // zeN bf16 transposed: [b*T+t][c], 16B per t-row (8 c's)
#pragma unroll
  for (int m = 0; m < 4; ++m) {
    int t = t0 + tx * 4 + m;
    unsigned short us[8];
#pragma unroll
    for (int j = 0; j < 8; ++j) us[j] = f2bf_rne(acc[j][m] + bias[j]);
    *(uint4*)&zeN[(size_t)(b * T_ + t) * CD_ + c0 + ty * 8] = *(uint4*)&us[0];
  }
}

// ---- K2: single MFMA scan storing per-64-code-tile row maxima (bf16) ----
// R8 scan geometry (proven: 0 conflicts, 2 blk/CU): 4 waves x 64 rows,
// 64-code dbuf LDS tiles via global_load_lds + both-sides XOR swizzle.
// Per tile: tile-max per row (in-lane over cf, butterfly over 16 lanes),
// stored to tmax[row][cq*16+t]. No atomics, no caps.
__global__ __launch_bounds__(256, 2) void vq_scan0(
    const unsigned short* __restrict__ zeN, const unsigned short* __restrict__ cbb,
    const float* __restrict__ c2, unsigned short* __restrict__ tmax) {
  __shared__ __align__(16) unsigned short smem[2][TILE_CODES * CD_];  // 2 x 32 KB
  int tid = threadIdx.x;
  int w = tid >> 6, l = tid & 63;
  int lrow = l & 15, lg = l >> 4;
  int rowbase = blockIdx.x * SCAN_ROWS + w * ROWS_PER_WAVE;
  int cq = blockIdx.y;
  int cbase0 = cq * CODES_PER_SPLIT;

  // A fragments: 4 row-frags x 8 k-steps (16B contiguous k-slices)
  short8v a[4][8];
#pragma unroll
  for (int rf = 0; rf < 4; ++rf)
#pragma unroll
    for (int ks = 0; ks < 8; ++ks)
      a[rf][ks] = *(const short8v*)&zeN[((size_t)(rowbase + rf * 16 + lrow)) * CD_ + ks * 32 + lg * 8];

  int lhalf = l >> 5;
  int lcol = (l & 31) * 16;
  char* smem_b = (char*)&smem[0][0];
  const char* cbb_b = (const char*)cbb;
  int xsw = (lrow & 7) << 4;

  auto stage = [&](int buf, int cbase) {
#pragma unroll
    for (int r = 0; r < 8; ++r) {
      int code = w * 16 + r * 2 + lhalf;
      size_t goff = (size_t)(cbase + code) * 512 + (size_t)(lcol ^ ((code & 7) << 4));
      gload_lds16(cbb_b + goff, smem_b + buf * 32768 + (w * 8 + r) * 1024);
    }
  };

  stage(0, cbase0);
  __syncthreads();

  for (int t = 0; t < CODES_PER_SPLIT / TILE_CODES; ++t) {
    int buf = t & 1;
    int cbase = cbase0 + t * TILE_CODES;
    if (t + 1 < CODES_PER_SPLIT / TILE_CODES)
      stage(buf ^ 1, cbase + TILE_CODES);

    const char* bufb = smem_b + buf * 32768;
    float tms[16];
#pragma unroll
    for (int s = 0; s < 16; ++s) tms[s] = -3.4e38f;

#pragma unroll
    for (int cf = 0; cf < 4; ++cf) {
      const char* bbase = bufb + (cf * 16 + lrow) * 512;
      float half_c2 = 0.5f * c2[cbase + cf * 16 + lrow];
      float4v acc[4];
#pragma unroll
      for (int rf = 0; rf < 4; ++rf) acc[rf] = (float4v){0.f, 0.f, 0.f, 0.f};
#pragma unroll
      for (int ks = 0; ks < 8; ++ks) {
        short8v bfrag = *(const short8v*)(bbase + ((ks * 64 + lg * 16) ^ xsw));
        acc[0] = __builtin_amdgcn_mfma_f32_16x16x32_bf16(a[0][ks], bfrag, acc[0], 0, 0, 0);
        acc[1] = __builtin_amdgcn_mfma_f32_16x16x32_bf16(a[1][ks], bfrag, acc[1], 0, 0, 0);
        acc[2] = __builtin_amdgcn_mfma_f32_16x16x32_bf16(a[2][ks], bfrag, acc[2], 0, 0, 0);
        acc[3] = __builtin_amdgcn_mfma_f32_16x16x32_bf16(a[3][ks], bfrag, acc[3], 0, 0, 0);
      }
#pragma unroll
      for (int rf = 0; rf < 4; ++rf)
#pragma unroll
        for (int rg = 0; rg < 4; ++rg)
          tms[rf * 4 + rg] = fmaxf(tms[rf * 4 + rg], acc[rf][rg] - half_c2);
    }

    // butterfly each slot's tile-max over the 16-lane (lrow) group; lane
    // lrow==s of each lg group writes its row's entry.
    int gt = cq * (CODES_PER_SPLIT / TILE_CODES) + t;
#pragma unroll
    for (int s = 0; s < 16; ++s) {
      float v = tms[s];
      v = fmaxf(v, __shfl_xor(v, 1));
      v = fmaxf(v, __shfl_xor(v, 2));
      v = fmaxf(v, __shfl_xor(v, 4));
      v = fmaxf(v, __shfl_xor(v, 8));
      if (lrow == s) {
        int row = rowbase + (s >> 2) * 16 + lg * 4 + (s & 3);
        tmax[(size_t)row * NTILE + gt] = f2bf_rne(v);
      }
    }
    __syncthreads();
  }
}

// ---- K3: finalize — exact fp32 argmin over flagged tiles ----
// 16 lanes per row. rowmax from tmax; flag tiles >= rowmax - DELTA; for each
// flagged tile compute exact ||ze-c||^2 (proven rescore formula) and take
// lexicographic (dist, idx) min, iterating in ascending code order.
__global__ __launch_bounds__(256) void vq_final(
    const float* __restrict__ ze, const float* __restrict__ cb,
    const unsigned short* __restrict__ tmax,
    float* __restrict__ out, int* __restrict__ idx_ws) {
  int tid = threadIdx.x;
  int n = blockIdx.x * 16 + (tid >> 4);
  int j = tid & 15;
  int b = n >> 11, t = n & (T_ - 1);

  // preload ze row: lane j holds dims j, j+16, ..., j+240
  float zev[16];
#pragma unroll
  for (int i = 0; i < 16; ++i)
    zev[i] = ze[((size_t)(b * CD_ + j + 16 * i)) * T_ + t];

  const unsigned short* tr = tmax + (size_t)n * NTILE;
  // rowmax: 8 bf16 per lane
  uint4 tv = *(const uint4*)&tr[j * 8];
  unsigned uu[4] = {tv.x, tv.y, tv.z, tv.w};
  float m = -3.4e38f;
#pragma unroll
  for (int i = 0; i < 4; ++i) {
    m = fmaxf(m, __uint_as_float(uu[i] << 16));
    m = fmaxf(m, __uint_as_float(uu[i] & 0xffff0000u));
  }
  m = fmaxf(m, __shfl_xor(m, 1));
  m = fmaxf(m, __shfl_xor(m, 2));
  m = fmaxf(m, __shfl_xor(m, 4));
  m = fmaxf(m, __shfl_xor(m, 8));
  float thr = m - DELTA;

  float bd = 3.4e38f; int bi = 0x7fffffff;
  for (int gt = 0; gt < NTILE; ++gt) {
    float tm = bf2f(tr[gt]);
    if (tm < thr) continue;
    int cbase = (gt >> 4) * CODES_PER_SPLIT + (gt & 15) * TILE_CODES;
    for (int c = 0; c < TILE_CODES; ++c) {
      const float* cr = cb + (size_t)(cbase + c) * CD_ + j;
      float d = 0.f;
#pragma unroll
      for (int i = 0; i < 16; ++i) {
        float diff = zev[i] - cr[16 * i];
        d = fmaf(diff, diff, d);
      }
      d += __shfl_xor(d, 1);
      d += __shfl_xor(d, 2);
      d += __shfl_xor(d, 4);
      d += __shfl_xor(d, 8);
      int code = cbase + c;
      if (d < bd || (d == bd && code < bi)) { bd = d; bi = code; }
    }
  }
  if (j == 0) {
    idx_ws[n] = bi;
    out[OUT_IDX + n] = (float)bi;
  }
}

// ---- K4 (MFMA): z_q = w_out @ codebook[idx] + out_b ----
__global__ __launch_bounds__(256, 2) void zq_mfma(
    const unsigned short* __restrict__ wob, const unsigned short* __restrict__ cbb,
    const float* __restrict__ out_bias, const int* __restrict__ idx,
    float* __restrict__ out) {
  __shared__ __align__(16) unsigned short Bs[64 * CD_];  // 32 KB
  __shared__ int idxs[64];
  int tid = threadIdx.x;
  int w = tid >> 6, l = tid & 63;
  int lrow = l & 15, lg = l >> 4;
  int t0 = blockIdx.x * 64, d0 = blockIdx.y * 256, b = blockIdx.z;
  int rowbase = d0 + w * 64;

  if (tid < 64) idxs[tid] = idx[b * T_ + t0 + tid];

  short8v a[4][8];
#pragma unroll
  for (int rf = 0; rf < 4; ++rf)
#pragma unroll
    for (int ks = 0; ks < 8; ++ks)
      a[rf][ks] = *(const short8v*)&wob[((size_t)(rowbase + rf * 16 + lrow)) * CD_ + ks * 32 + lg * 8];

  __syncthreads();  // idxs ready

  int lhalf = l >> 5;
  int lcol = (l & 31) * 16;
  char* Bs_b = (char*)&Bs[0];
  const char* cbb_b = (const char*)cbb;
#pragma unroll
  for (int r = 0; r < 8; ++r) {
    int t = w * 16 + r * 2 + lhalf;
    int row = idxs[t];
    size_t goff = (size_t)row * 512 + (size_t)(lcol ^ ((t & 7) << 4));
    gload_lds16(cbb_b + goff, Bs_b + (w * 8 + r) * 1024);
  }
  __syncthreads();  // drains vmcnt

  int xsw = (lrow & 7) << 4;
  float4v acc[4][4];
#pragma unroll
  for (int rf = 0; rf < 4; ++rf)
#pragma unroll
    for (int cf = 0; cf < 4; ++cf) acc[rf][cf] = (float4v){0.f, 0.f, 0.f, 0.f};
#pragma unroll
  for (int cf = 0; cf < 4; ++cf) {
    const char* bbase = Bs_b + (cf * 16 + lrow) * 512;
#pragma unroll
    for (int ks = 0; ks < 8; ++ks) {
      short8v bfrag = *(const short8v*)(bbase + ((ks * 64 + lg * 16) ^ xsw));
      acc[0][cf] = __builtin_amdgcn_mfma_f32_16x16x32_bf16(a[0][ks], bfrag, acc[0][cf], 0, 0, 0);
      acc[1][cf] = __builtin_amdgcn_mfma_f32_16x16x32_bf16(a[1][ks], bfrag, acc[1][cf], 0, 0, 0);
      acc[2][cf] = __builtin_amdgcn_mfma_f32_16x16x32_bf16(a[2][ks], bfrag, acc[2][cf], 0, 0, 0);
      acc[3][cf] = __builtin_amdgcn_mfma_f32_16x16x32_bf16(a[3][ks], bfrag, acc[3][cf], 0, 0, 0);
    }
  }
#pragma unroll
  for (int rf = 0; rf < 4; ++rf) {
    float bias[4];
#pragma unroll
    for (int rg = 0; rg < 4; ++rg) bias[rg] = out_bias[rowbase + rf * 16 + lg * 4 + rg];
#pragma unroll
    for (int cf = 0; cf < 4; ++cf) {
      int t = t0 + cf * 16 + lrow;
#pragma unroll
      for (int rg = 0; rg < 4; ++rg) {
        int d = rowbase + rf * 16 + lg * 4 + rg;
        out[OUT_ZQ + (size_t)(b * D_ + d) * T_ + t] = acc[rf][cf][rg] + bias[rg];
      }
    }
  }
}

extern "C" void kernel_launch(void* const* d_in, const int* in_sizes, int n_in,
                              void* d_out, int out_size, void* d_ws,
                              size_t ws_size, hipStream_t stream) {
  const float* z     = (const float*)d_in[0];
  const float* in_v  = (const float*)d_in[1];
  const float* in_g  = (const float*)d_in[2];
  const float* in_b  = (const float*)d_in[3];
  const float* out_v = (const float*)d_in[4];
  const float* out_g = (const float*)d_in[5];
  const float* out_b = (const float*)d_in[6];
  const float* cb    = (const float*)d_in[7];
  float* out = (float*)d_out;
  float* ws  = (float*)d_ws;

  unsigned short* zeN = (unsigned short*)(ws + WS_ZEN);
  unsigned short* cbb = (unsigned short*)(ws + WS_CBB);
  float* w_inT  = ws + WS_WINT;
  unsigned short* wob = (unsigned short*)(ws + WS_WOB);
  float* c2     = ws + WS_C2;
  unsigned short* tmax = (unsigned short*)(ws + WS_TMAX);
  int*   idxw   = (int*)(ws + WS_IDX);

  prep_all<<<CD_ + D_ + CS_ / 4 + CS_ * CD_ / 8 / 256, 256, 0, stream>>>(
      in_v, in_g, out_v, out_g, cb, w_inT, wob, c2, cbb);

  ze_gemm<<<dim3(T_ / 128, CD_ / 64, B_), 256, 0, stream>>>(
      z, w_inT, in_b, out, zeN);

  vq_scan0<<<dim3(N_ / SCAN_ROWS, NSPLIT), 256, 0, stream>>>(
      zeN, cbb, c2, tmax);
  vq_final<<<N_ / 16, 256, 0, stream>>>(out + OUT_ZE, cb, tmax, out, idxw);

  zq_mfma<<<dim3(T_ / 64, D_ / 256, B_), 256, 0, stream>>>(wob, cbb, out_b, idxw, out);
}

// Round 12
// 404.362 us; speedup vs baseline: 1.8662x; 1.8662x over previous
//
#include <hip/hip_runtime.h>
#include <math.h>

// Problem constants
#define B_  8
#define D_  1024
#define T_  2048
#define CD_ 256
#define CS_ 8192
#define N_  (B_*T_)

#define NSPLIT 8
#define CODES_PER_SPLIT (CS_/NSPLIT)   // 1024
#define NT_SPLIT (CODES_PER_SPLIT/64)  // 16 tiles per split
#define DELTA 1.5f                     // score-units; >> 2*bf16 dot error

// scan geometry: 4 waves * 64 rows = 256 rows/block; 64-code LDS tiles
#define ROWS_PER_WAVE 64
#define SCAN_ROWS 256
#define TILE_CODES 64

// ws layout (float offsets). Total ~15.9 MB (proven size range).
#define WS_ZEN   0                        // bf16 [N][256]   (2,097,152 float slots)
#define WS_CBB   2097152                  // bf16 [CS][256]  (1,048,576)
#define WS_WINT  (WS_CBB + 1048576)       // f32 [D][CD]
#define WS_WOB   (WS_WINT + D_*CD_)       // bf16 [D][CD] (131072 float slots)
#define WS_C2    (WS_WOB + D_*CD_/2)      // f32 [CS]
#define WS_BESTQ (WS_C2 + CS_)            // f32 [NSPLIT][N]; becomes thr
#define WS_CNT   (WS_BESTQ + NSPLIT*N_)   // int [N]
#define WS_CAND  (WS_CNT + N_)            // int [N][16]
#define WS_IDX   (WS_CAND + N_*16)        // int [N]

// d_out layout (floats): z_q, indices(as float), z_e
#define OUT_ZQ  0
#define OUT_IDX (B_*D_*T_)
#define OUT_ZE  (OUT_IDX + B_*T_)

using short8v = __attribute__((ext_vector_type(8))) short;
using float4v = __attribute__((ext_vector_type(4))) float;

__device__ __forceinline__ float wave_sum64(float v) {
#pragma unroll
  for (int off = 32; off >= 1; off >>= 1) v += __shfl_xor(v, off);
  return v;
}

__device__ __forceinline__ unsigned short f2bf_rne(float f) {
  unsigned int u = __float_as_uint(f);
  u += 0x7fffu + ((u >> 16) & 1u);
  return (unsigned short)(u >> 16);
}

__device__ __forceinline__ void gload_lds16(const void* g, void* l) {
  __builtin_amdgcn_global_load_lds(
      (const __attribute__((address_space(1))) void*)g,
      (__attribute__((address_space(3))) void*)l, 16, 0, 0);
}

// ---- fused prep: one kernel, block-range dispatch ----
// [0,256): w_inT  [256,1280): wob  [1280,3328): c2  [3328,4352): cbb
__global__ __launch_bounds__(256) void prep_all(
    const float* __restrict__ in_v, const float* __restrict__ in_g,
    const float* __restrict__ out_v, const float* __restrict__ out_g,
    const float* __restrict__ cb,
    float* __restrict__ w_inT, unsigned short* __restrict__ wob,
    float* __restrict__ c2, unsigned short* __restrict__ cbb) {
  __shared__ float sh[4];
  int blk = blockIdx.x, tid = threadIdx.x;
  if (blk < CD_) {
    int c = blk;
    float v[4]; float s = 0.f;
#pragma unroll
    for (int i = 0; i < 4; ++i) {
      v[i] = in_v[c * D_ + tid + 256 * i];
      s = fmaf(v[i], v[i], s);
    }
    s = wave_sum64(s);
    if ((tid & 63) == 0) sh[tid >> 6] = s;
    __syncthreads();
    float tot = sh[0] + sh[1] + sh[2] + sh[3];
    float scale = in_g[c] / sqrtf(tot);
#pragma unroll
    for (int i = 0; i < 4; ++i)
      w_inT[(tid + 256 * i) * CD_ + c] = v[i] * scale;
  } else if (blk < CD_ + D_) {
    int d = blk - CD_;
    float v = out_v[d * CD_ + tid];
    float s = wave_sum64(v * v);
    if ((tid & 63) == 0) sh[tid >> 6] = s;
    __syncthreads();
    float tot = sh[0] + sh[1] + sh[2] + sh[3];
    float scale = out_g[d] / sqrtf(tot);
    wob[d * CD_ + tid] = f2bf_rne(v * scale);
  } else if (blk < CD_ + D_ + CS_ / 4) {
    int w = tid >> 6, lane = tid & 63;
    int s = (blk - CD_ - D_) * 4 + w;
    float acc = 0.f;
#pragma unroll
    for (int i = 0; i < 4; ++i) {
      float v = cb[(size_t)s * CD_ + lane + 64 * i];
      acc = fmaf(v, v, acc);
    }
    acc = wave_sum64(acc);
    if (lane == 0) c2[s] = acc;
  } else {
    size_t i = (size_t)(blk - CD_ - D_ - CS_ / 4) * 256 + tid;  // octet index
    float4 v0 = *(const float4*)&cb[i * 8];
    float4 v1 = *(const float4*)&cb[i * 8 + 4];
    float f[8] = {v0.x, v0.y, v0.z, v0.w, v1.x, v1.y, v1.z, v1.w};
    unsigned short us[8];
#pragma unroll
    for (int m = 0; m < 8; ++m) us[m] = f2bf_rne(f[m]);
    *(uint4*)&cbb[i * 8] = *(uint4*)&us[0];
  }
}

// ---- K1: z_e = w_in @ z + b, fused transpose+bf16 (zeN) epilogue ----
// R8 geometry (tile 64c x 128t, TK=32, 256 thr, 8c x 4t, 2 blk/CU) with
// counted-vmcnt barrier discipline: stage(next) -> s_waitcnt vmcnt(6)
// (waits only the CURRENT K-tile's 6 loads; next-tile loads stay in
// flight across the barrier) -> s_barrier -> compute -> s_barrier.
// Per-output K-order = sequential kk (bit-identical z_e to R8).
__global__ __launch_bounds__(256) void ze_gemm(
    const float* __restrict__ z, const float* __restrict__ w_inT,
    const float* __restrict__ in_b, float* __restrict__ out,
    unsigned short* __restrict__ zeN) {
  __shared__ __align__(16) float At[2][32 * 64];    // 8 KB each
  __shared__ __align__(16) float Bt[2][32 * 128];   // 16 KB each
  int tid = threadIdx.x, tx = tid & 31, ty = tid >> 5;
  int w = tid >> 6, l = tid & 63;
  int t0 = blockIdx.x * 128, c0 = blockIdx.y * 64, b = blockIdx.z;
  const float* zb = z + (size_t)b * D_ * T_;

  auto stage = [&](int buf, int kc) {
#pragma unroll
    for (int i = 0; i < 2; ++i) {
      int g = w * 2 + i;
      int kk = g * 4 + (l >> 4);
      int c = (l & 15) * 4;
      gload_lds16(&w_inT[(size_t)(kc + kk) * CD_ + c0 + c], &At[buf][g * 256]);
    }
#pragma unroll
    for (int i = 0; i < 4; ++i) {
      int g = w * 4 + i;
      int kk = g * 2 + (l >> 5);
      int t = (l & 31) * 4;
      gload_lds16(&zb[(size_t)(kc + kk) * T_ + t0 + t], &Bt[buf][g * 256]);
    }
  };

  float acc[8][4] = {};
  stage(0, 0);
  int cur = 0;
  for (int kt = 0; kt < D_ / 32; ++kt) {
    if (kt + 1 < D_ / 32) {
      stage(cur ^ 1, (kt + 1) * 32);
      asm volatile("s_waitcnt vmcnt(6)" ::: "memory");
    } else {
      asm volatile("s_waitcnt vmcnt(0)" ::: "memory");
    }
    __builtin_amdgcn_sched_barrier(0);
    __builtin_amdgcn_s_barrier();  // current tile fully in LDS
#pragma unroll 8
    for (int kk = 0; kk < 32; ++kk) {
      float a[8], bv[4];
      *(float4*)&a[0] = *(const float4*)&At[cur][kk * 64 + ty * 8];
      *(float4*)&a[4] = *(const float4*)&At[cur][kk * 64 + ty * 8 + 4];
      *(float4*)&bv[0] = *(const float4*)&Bt[cur][kk * 128 + tx * 4];
#pragma unroll
      for (int j = 0; j < 8; ++j)
#pragma unroll
        for (int m = 0; m < 4; ++m)
          acc[j][m] = fmaf(a[j], bv[m], acc[j][m]);
    }
    __builtin_amdgcn_s_barrier();  // all reads of cur done before restage
    cur ^= 1;
  }

  float bias[8];
#pragma unroll
  for (int j = 0; j < 8; ++j) bias[j] = in_b[c0 + ty * 8 + j];

  // z_e fp32: [b][c][t]
#pragma unroll
  for (int j = 0; j < 8; ++j) {
    int c = c0 + ty * 8 + j;
    float4 o;
    o.x = acc[j][0] + bias[j]; o.y = acc[j][1] + bias[j];
    o.z = acc[j][2] + bias[j]; o.w = acc[j][3] + bias[j];
    *(float4*)&out[OUT_ZE + (size_t)(b * CD_ + c) * T_ + t0 + tx * 4] = o;
  }
  // zeN bf16 transposed: [b*T+t][c], 16B per t-row (8 c's)
#pragma unroll
  for (int m = 0; m < 4; ++m) {
    int t = t0 + tx * 4 + m;
    unsigned short us[8];
#pragma unroll
    for (int j = 0; j < 8; ++j) us[j] = f2bf_rne(acc[j][m] + bias[j]);
    *(uint4*)&zeN[(size_t)(b * T_ + t) * CD_ + c0 + ty * 8] = *(uint4*)&us[0];
  }
}

// ---- K2: MFMA coarse scan, two-pass (proven R8 structure + counted vmcnt).
// Per tile: load c2 (current) FIRST, then stage(next) -> vmcnt(8) waits only
// the current tile's 8 staged loads (safe under compiler reorder of the c2
// loads: stage(t) is oldest in FIFO either way) -> barrier -> compute ->
// barrier. Score arithmetic identical to R8 -> identical indices.
template <int COLLECT>
__global__ __launch_bounds__(256, 2) void vq_scan(
    const unsigned short* __restrict__ zeN, const unsigned short* __restrict__ cbb,
    const float* __restrict__ c2, float* __restrict__ bestq,
    int* __restrict__ cnt, int* __restrict__ cand) {
  __shared__ __align__(16) unsigned short smem[2][TILE_CODES * CD_];  // 2 x 32 KB
  int tid = threadIdx.x;
  int w = tid >> 6, l = tid & 63;
  int lrow = l & 15, lg = l >> 4;
  int rowbase = blockIdx.x * SCAN_ROWS + w * ROWS_PER_WAVE;
  int cq = blockIdx.y;
  int cbase0 = cq * CODES_PER_SPLIT;

  if (COLLECT == 0 && cq == 0)
    cnt[blockIdx.x * SCAN_ROWS + tid] = 0;

  short8v a[4][8];
#pragma unroll
  for (int rf = 0; rf < 4; ++rf)
#pragma unroll
    for (int ks = 0; ks < 8; ++ks)
      a[rf][ks] = *(const short8v*)&zeN[((size_t)(rowbase + rf * 16 + lrow)) * CD_ + ks * 32 + lg * 8];

  float best[16];
  float thr[16];
#pragma unroll
  for (int s = 0; s < 16; ++s) best[s] = -3.4e38f;
  if (COLLECT) {
#pragma unroll
    for (int s = 0; s < 16; ++s) {
      int rf = s >> 2, rg = s & 3;
      thr[s] = bestq[rowbase + rf * 16 + lg * 4 + rg];  // rowmax - DELTA
    }
  }

  int lhalf = l >> 5;
  int lcol = (l & 31) * 16;
  char* smem_b = (char*)&smem[0][0];
  const char* cbb_b = (const char*)cbb;
  int xsw = (lrow & 7) << 4;

  auto stage = [&](int buf, int cbase) {
#pragma unroll
    for (int r = 0; r < 8; ++r) {
      int code = w * 16 + r * 2 + lhalf;
      size_t goff = (size_t)(cbase + code) * 512 + (size_t)(lcol ^ ((code & 7) << 4));
      gload_lds16(cbb_b + goff, smem_b + buf * 32768 + (w * 8 + r) * 1024);
    }
  };

  stage(0, cbase0);

  for (int t = 0; t < NT_SPLIT; ++t) {
    int buf = t & 1;
    int cbase = cbase0 + t * TILE_CODES;

    // current tile's c2 (issued before next stage so stage(t) stays oldest)
    float hc2[4];
#pragma unroll
    for (int cf = 0; cf < 4; ++cf) hc2[cf] = 0.5f * c2[cbase + cf * 16 + lrow];

    if (t + 1 < NT_SPLIT) {
      stage(buf ^ 1, cbase + TILE_CODES);
      asm volatile("s_waitcnt vmcnt(8)" ::: "memory");
    } else {
      asm volatile("s_waitcnt vmcnt(0)" ::: "memory");
    }
    __builtin_amdgcn_sched_barrier(0);
    __builtin_amdgcn_s_barrier();  // tile t fully in LDS (all waves)

    const char* bufb = smem_b + buf * 32768;
#pragma unroll
    for (int cf = 0; cf < 4; ++cf) {
      const char* bbase = bufb + (cf * 16 + lrow) * 512;
      float4v acc[4];
#pragma unroll
      for (int rf = 0; rf < 4; ++rf) acc[rf] = (float4v){0.f, 0.f, 0.f, 0.f};
#pragma unroll
      for (int ks = 0; ks < 8; ++ks) {
        short8v bfrag = *(const short8v*)(bbase + ((ks * 64 + lg * 16) ^ xsw));
        acc[0] = __builtin_amdgcn_mfma_f32_16x16x32_bf16(a[0][ks], bfrag, acc[0], 0, 0, 0);
        acc[1] = __builtin_amdgcn_mfma_f32_16x16x32_bf16(a[1][ks], bfrag, acc[1], 0, 0, 0);
        acc[2] = __builtin_amdgcn_mfma_f32_16x16x32_bf16(a[2][ks], bfrag, acc[2], 0, 0, 0);
        acc[3] = __builtin_amdgcn_mfma_f32_16x16x32_bf16(a[3][ks], bfrag, acc[3], 0, 0, 0);
      }
      int ci = cbase + cf * 16 + lrow;
#pragma unroll
      for (int rf = 0; rf < 4; ++rf)
#pragma unroll
        for (int rg = 0; rg < 4; ++rg) {
          float sc = acc[rf][rg] - hc2[cf];
          int slot = rf * 4 + rg;
          if (COLLECT) {
            if (sc >= thr[slot]) {
              int row = rowbase + rf * 16 + lg * 4 + rg;
              int pos = atomicAdd(&cnt[row], 1);
              if (pos < 16) cand[row * 16 + pos] = ci;
            }
          } else {
            best[slot] = fmaxf(best[slot], sc);
          }
        }
    }
    __builtin_amdgcn_s_barrier();  // all reads of buf done before restage
  }

  if (!COLLECT) {
#pragma unroll
    for (int s = 0; s < 16; ++s) {
      float v = best[s];
#pragma unroll
      for (int off = 1; off < 16; off <<= 1) v = fmaxf(v, __shfl_xor(v, off));
      best[s] = v;
    }
    if (lrow == 0) {
#pragma unroll
      for (int s = 0; s < 16; ++s) {
        int rf = s >> 2, rg = s & 3;
        bestq[cq * N_ + rowbase + rf * 16 + lg * 4 + rg] = best[s];
      }
    }
  }
}

// ---- fold split maxima into per-row threshold, in place (row 0 of bestq) ----
__global__ __launch_bounds__(256) void vq_rowthr(float* __restrict__ bestq) {
  int n = blockIdx.x * 256 + threadIdx.x;
  float m = bestq[n];
#pragma unroll
  for (int q = 1; q < NSPLIT; ++q) m = fmaxf(m, bestq[q * N_ + n]);
  bestq[n] = m - DELTA;
}

// ---- exact fp32 rescore of candidates; lexicographic (dist, idx) min ----
__global__ __launch_bounds__(256) void vq_rescore(
    const float* __restrict__ ze, const float* __restrict__ cb,
    const int* __restrict__ cnt, const int* __restrict__ cand,
    float* __restrict__ out, int* __restrict__ idx_ws) {
  int tid = threadIdx.x;
  int n = blockIdx.x * 64 + (tid >> 2);
  int j = tid & 3;
  int b = n >> 11, t = n & (T_ - 1);
  const float* zr = ze + ((size_t)b * CD_) * T_ + t;  // element k at zr[k*T_]
  int m = cnt[n]; if (m > 16) m = 16;
  float bd = 3.4e38f; int bi = 0x7fffffff;
  for (int i = 0; i < m; ++i) {
    int c = cand[n * 16 + i];
    const float* cr = cb + (size_t)c * CD_;
    float d = 0.f;
    for (int k = j; k < CD_; k += 4) {
      float diff = zr[(size_t)k * T_] - cr[k];
      d = fmaf(diff, diff, d);
    }
    d += __shfl_xor(d, 1);
    d += __shfl_xor(d, 2);
    if (d < bd || (d == bd && c < bi)) { bd = d; bi = c; }
  }
  if (j == 0) {
    idx_ws[n] = bi;
    out[OUT_IDX + n] = (float)bi;
  }
}

// ---- K3 (MFMA): z_q = w_out @ codebook[idx] + out_b ----
__global__ __launch_bounds__(256, 2) void zq_mfma(
    const unsigned short* __restrict__ wob, const unsigned short* __restrict__ cbb,
    const float* __restrict__ out_bias, const int* __restrict__ idx,
    float* __restrict__ out) {
  __shared__ __align__(16) unsigned short Bs[64 * CD_];  // 32 KB
  __shared__ int idxs[64];
  int tid = threadIdx.x;
  int w = tid >> 6, l = tid & 63;
  int lrow = l & 15, lg = l >> 4;
  int t0 = blockIdx.x * 64, d0 = blockIdx.y * 256, b = blockIdx.z;
  int rowbase = d0 + w * 64;

  if (tid < 64) idxs[tid] = idx[b * T_ + t0 + tid];

  short8v a[4][8];
#pragma unroll
  for (int rf = 0; rf < 4; ++rf)
#pragma unroll
    for (int ks = 0; ks < 8; ++ks)
      a[rf][ks] = *(const short8v*)&wob[((size_t)(rowbase + rf * 16 + lrow)) * CD_ + ks * 32 + lg * 8];

  __syncthreads();  // idxs ready

  int lhalf = l >> 5;
  int lcol = (l & 31) * 16;
  char* Bs_b = (char*)&Bs[0];
  const char* cbb_b = (const char*)cbb;
#pragma unroll
  for (int r = 0; r < 8; ++r) {
    int t = w * 16 + r * 2 + lhalf;
    int row = idxs[t];
    size_t goff = (size_t)row * 512 + (size_t)(lcol ^ ((t & 7) << 4));
    gload_lds16(cbb_b + goff, Bs_b + (w * 8 + r) * 1024);
  }
  __syncthreads();  // drains vmcnt

  int xsw = (lrow & 7) << 4;
  float4v acc[4][4];
#pragma unroll
  for (int rf = 0; rf < 4; ++rf)
#pragma unroll
    for (int cf = 0; cf < 4; ++cf) acc[rf][cf] = (float4v){0.f, 0.f, 0.f, 0.f};
#pragma unroll
  for (int cf = 0; cf < 4; ++cf) {
    const char* bbase = Bs_b + (cf * 16 + lrow) * 512;
#pragma unroll
    for (int ks = 0; ks < 8; ++ks) {
      short8v bfrag = *(const short8v*)(bbase + ((ks * 64 + lg * 16) ^ xsw));
      acc[0][cf] = __builtin_amdgcn_mfma_f32_16x16x32_bf16(a[0][ks], bfrag, acc[0][cf], 0, 0, 0);
      acc[1][cf] = __builtin_amdgcn_mfma_f32_16x16x32_bf16(a[1][ks], bfrag, acc[1][cf], 0, 0, 0);
      acc[2][cf] = __builtin_amdgcn_mfma_f32_16x16x32_bf16(a[2][ks], bfrag, acc[2][cf], 0, 0, 0);
      acc[3][cf] = __builtin_amdgcn_mfma_f32_16x16x32_bf16(a[3][ks], bfrag, acc[3][cf], 0, 0, 0);
    }
  }
#pragma unroll
  for (int rf = 0; rf < 4; ++rf) {
    float bias[4];
#pragma unroll
    for (int rg = 0; rg < 4; ++rg) bias[rg] = out_bias[rowbase + rf * 16 + lg * 4 + rg];
#pragma unroll
    for (int cf = 0; cf < 4; ++cf) {
      int t = t0 + cf * 16 + lrow;
#pragma unroll
      for (int rg = 0; rg < 4; ++rg) {
        int d = rowbase + rf * 16 + lg * 4 + rg;
        out[OUT_ZQ + (size_t)(b * D_ + d) * T_ + t] = acc[rf][cf][rg] + bias[rg];
      }
    }
  }
}

extern "C" void kernel_launch(void* const* d_in, const int* in_sizes, int n_in,
                              void* d_out, int out_size, void* d_ws,
                              size_t ws_size, hipStream_t stream) {
  const float* z     = (const float*)d_in[0];
  const float* in_v  = (const float*)d_in[1];
  const float* in_g  = (const float*)d_in[2];
  const float* in_b  = (const float*)d_in[3];
  const float* out_v = (const float*)d_in[4];
  const float* out_g = (const float*)d_in[5];
  const float* out_b = (const float*)d_in[6];
  const float* cb    = (const float*)d_in[7];
  float* out = (float*)d_out;
  float* ws  = (float*)d_ws;

  unsigned short* zeN = (unsigned short*)(ws + WS_ZEN);
  unsigned short* cbb = (unsigned short*)(ws + WS_CBB);
  float* w_inT  = ws + WS_WINT;
  unsigned short* wob = (unsigned short*)(ws + WS_WOB);
  float* c2     = ws + WS_C2;
  float* bestq  = ws + WS_BESTQ;
  int*   cnt    = (int*)(ws + WS_CNT);
  int*   cand   = (int*)(ws + WS_CAND);
  int*   idxw   = (int*)(ws + WS_IDX);

  prep_all<<<CD_ + D_ + CS_ / 4 + CS_ * CD_ / 8 / 256, 256, 0, stream>>>(
      in_v, in_g, out_v, out_g, cb, w_inT, wob, c2, cbb);

  ze_gemm<<<dim3(T_ / 128, CD_ / 64, B_), 256, 0, stream>>>(
      z, w_inT, in_b, out, zeN);

  vq_scan<0><<<dim3(N_ / SCAN_ROWS, NSPLIT), 256, 0, stream>>>(
      zeN, cbb, c2, bestq, cnt, cand);
  vq_rowthr<<<N_ / 256, 256, 0, stream>>>(bestq);
  vq_scan<1><<<dim3(N_ / SCAN_ROWS, NSPLIT), 256, 0, stream>>>(
      zeN, cbb, c2, bestq, cnt, cand);
  vq_rescore<<<N_ / 64, 256, 0, stream>>>(out + OUT_ZE, cb, cnt, cand, out, idxw);

  zq_mfma<<<dim3(T_ / 64, D_ / 256, B_), 256, 0, stream>>>(wob, cbb, out_b, idxw, out);
}

// Round 13
// 327.863 us; speedup vs baseline: 2.3016x; 1.2333x over previous
//
#include <hip/hip_runtime.h>
#include <math.h>

// Problem constants
#define B_  8
#define D_  1024
#define T_  2048
#define CD_ 256
#define CS_ 8192
#define N_  (B_*T_)

#define NSPLIT 8
#define CODES_PER_SPLIT (CS_/NSPLIT)   // 1024
#define NT_SPLIT (CODES_PER_SPLIT/64)  // 16 tiles per split
#define DELTA 1.5f                     // score-units; >> 2*bf16 dot error

// scan geometry: 4 waves * 64 rows = 256 rows/block; 64-code LDS tiles
#define ROWS_PER_WAVE 64
#define SCAN_ROWS 256
#define TILE_CODES 64

// ws layout (float offsets). Total 15.9 MB (proven range). bestq lives in
// d_out's z_q region (free scratch until zq_mfma overwrites it).
#define WS_ZEN   0                        // bf16 [N][256]   (2,097,152 float slots)
#define WS_CBB   2097152                  // bf16 [CS][256]  (1,048,576)
#define WS_WH    (WS_CBB + 1048576)       // bf16 [CD][D] hi   (131072)
#define WS_WM    (WS_WH + 131072)         // bf16 [CD][D] mid
#define WS_WL    (WS_WM + 131072)         // bf16 [CD][D] lo
#define WS_WOB   (WS_WL + 131072)         // bf16 [D][CD]
#define WS_C2    (WS_WOB + 131072)        // f32 [CS]
#define WS_CNT   (WS_C2 + CS_)            // int [N]
#define WS_CAND  (WS_CNT + N_)            // int [N][16]
#define WS_IDX   (WS_CAND + N_*16)        // int [N]

// d_out layout (floats): z_q, indices(as float), z_e
#define OUT_ZQ  0
#define OUT_IDX (B_*D_*T_)
#define OUT_ZE  (OUT_IDX + B_*T_)

using short8v = __attribute__((ext_vector_type(8))) short;
using float4v = __attribute__((ext_vector_type(4))) float;

__device__ __forceinline__ float wave_sum64(float v) {
#pragma unroll
  for (int off = 32; off >= 1; off >>= 1) v += __shfl_xor(v, off);
  return v;
}

__device__ __forceinline__ unsigned short f2bf_rne(float f) {
  unsigned int u = __float_as_uint(f);
  u += 0x7fffu + ((u >> 16) & 1u);
  return (unsigned short)(u >> 16);
}

__device__ __forceinline__ float bf2f(unsigned short u) {
  return __uint_as_float(((unsigned)u) << 16);
}

__device__ __forceinline__ void gload_lds16(const void* g, void* l) {
  __builtin_amdgcn_global_load_lds(
      (const __attribute__((address_space(1))) void*)g,
      (__attribute__((address_space(3))) void*)l, 16, 0, 0);
}

// ---- fused prep: one kernel, block-range dispatch ----
// [0,256): w_in splits  [256,1280): wob  [1280,3328): c2  [3328,4352): cbb
__global__ __launch_bounds__(256) void prep_all(
    const float* __restrict__ in_v, const float* __restrict__ in_g,
    const float* __restrict__ out_v, const float* __restrict__ out_g,
    const float* __restrict__ cb,
    unsigned short* __restrict__ wh, unsigned short* __restrict__ wm,
    unsigned short* __restrict__ wl, unsigned short* __restrict__ wob,
    float* __restrict__ c2, unsigned short* __restrict__ cbb) {
  __shared__ float sh[4];
  int blk = blockIdx.x, tid = threadIdx.x;
  if (blk < CD_) {
    // w row c = in_g[c]*in_v[c,:]/||.|| (exact fp32), split bf16x3 (rne+trunc)
    int c = blk;
    float v[4]; float s = 0.f;
#pragma unroll
    for (int i = 0; i < 4; ++i) {
      v[i] = in_v[c * D_ + tid + 256 * i];
      s = fmaf(v[i], v[i], s);
    }
    s = wave_sum64(s);
    if ((tid & 63) == 0) sh[tid >> 6] = s;
    __syncthreads();
    float tot = sh[0] + sh[1] + sh[2] + sh[3];
    float scale = in_g[c] / sqrtf(tot);
#pragma unroll
    for (int i = 0; i < 4; ++i) {
      int d = tid + 256 * i;
      float x = v[i] * scale;
      unsigned short h = f2bf_rne(x);
      float r1 = x - bf2f(h);
      unsigned short m = (unsigned short)(__float_as_uint(r1) >> 16);
      float r2 = r1 - bf2f(m);
      unsigned short lo = (unsigned short)(__float_as_uint(r2) >> 16);
      wh[c * D_ + d] = h; wm[c * D_ + d] = m; wl[c * D_ + d] = lo;
    }
  } else if (blk < CD_ + D_) {
    int d = blk - CD_;
    float v = out_v[d * CD_ + tid];
    float s = wave_sum64(v * v);
    if ((tid & 63) == 0) sh[tid >> 6] = s;
    __syncthreads();
    float tot = sh[0] + sh[1] + sh[2] + sh[3];
    float scale = out_g[d] / sqrtf(tot);
    wob[d * CD_ + tid] = f2bf_rne(v * scale);
  } else if (blk < CD_ + D_ + CS_ / 4) {
    int w = tid >> 6, lane = tid & 63;
    int s = (blk - CD_ - D_) * 4 + w;
    float acc = 0.f;
#pragma unroll
    for (int i = 0; i < 4; ++i) {
      float v = cb[(size_t)s * CD_ + lane + 64 * i];
      acc = fmaf(v, v, acc);
    }
    acc = wave_sum64(acc);
    if (lane == 0) c2[s] = acc;
  } else {
    size_t i = (size_t)(blk - CD_ - D_ - CS_ / 4) * 256 + tid;  // octet index
    float4 v0 = *(const float4*)&cb[i * 8];
    float4 v1 = *(const float4*)&cb[i * 8 + 4];
    float f[8] = {v0.x, v0.y, v0.z, v0.w, v1.x, v1.y, v1.z, v1.w};
    unsigned short us[8];
#pragma unroll
    for (int m = 0; m < 8; ++m) us[m] = f2bf_rne(f[m]);
    *(uint4*)&cbb[i * 8] = *(uint4*)&us[0];
  }
}

// ---- K1 (MFMA, bf16x3 exact split): z_e = w_in @ z + b ----
// tile 64c x 128t, 256 thr, 4 waves (wave w owns t-range w*32..+32; rf=4 c,
// cf=2 t). K streamed BK=32, double-buffered. A = precomputed w-splits
// ([c][d] k-contig, b128 frag reads = 64 distinct 16B chunks -> conflict-
// free). B = z staged fp32 with 1040-B pair-stride pad (bank shift 4/pair ->
// b32 frag gathers are 2-way = free), split to bf16x3 in-register.
// 6-term product (hh,mh,hm,mm,hl,lh): dropped terms ~2^-25 -> z_e error
// ~1e-8, far below fp32 accumulation-order noise (which already passes).
__global__ __launch_bounds__(256, 2) void ze_mfma(
    const float* __restrict__ z,
    const unsigned short* __restrict__ whp, const unsigned short* __restrict__ wmp,
    const unsigned short* __restrict__ wlp, const float* __restrict__ in_b,
    float* __restrict__ out, unsigned short* __restrict__ zeN) {
  __shared__ __align__(16) char zbuf[2][16 * 1040];          // 2 x 16640 B
  __shared__ __align__(16) unsigned short abuf[2][3][2048];  // 2 x 12 KB
  int tid = threadIdx.x;
  int w = tid >> 6, l = tid & 63;
  int lrow = l & 15, lg = l >> 4;
  int t0 = blockIdx.x * 128, c0 = blockIdx.y * 64, b = blockIdx.z;
  const float* zb = z + (size_t)b * D_ * T_;
  char* zbuf_b = &zbuf[0][0];
  char* abuf_b = (char*)&abuf[0][0][0];

  auto stage = [&](int buf, int kc) {
    // z: 16 pair-calls (pair g = rows 2g,2g+1); wave w does g = 4w..4w+3
#pragma unroll
    for (int i = 0; i < 4; ++i) {
      int g = w * 4 + i;
      int row = 2 * g + (l >> 5);
      gload_lds16(&zb[(size_t)(kc + row) * T_ + t0 + (l & 31) * 4],
                  zbuf_b + buf * 16640 + g * 1040);
    }
    // A: 3 splits x 4 calls (16 c-rows each); wave w does call w per split
    int c = w * 16 + (l >> 2);
    int doff = (l & 3) * 8;
    gload_lds16(&whp[(size_t)(c0 + c) * D_ + kc + doff],
                abuf_b + buf * 12288 + w * 1024);
    gload_lds16(&wmp[(size_t)(c0 + c) * D_ + kc + doff],
                abuf_b + buf * 12288 + 4096 + w * 1024);
    gload_lds16(&wlp[(size_t)(c0 + c) * D_ + kc + doff],
                abuf_b + buf * 12288 + 8192 + w * 1024);
  };

  float4v acc[4][2];
#pragma unroll
  for (int rf = 0; rf < 4; ++rf)
#pragma unroll
    for (int cf = 0; cf < 2; ++cf) acc[rf][cf] = (float4v){0.f, 0.f, 0.f, 0.f};

  stage(0, 0);
  int cur = 0;
  for (int kt = 0; kt < D_ / 32; ++kt) {
    if (kt + 1 < D_ / 32) {
      stage(cur ^ 1, (kt + 1) * 32);
      asm volatile("s_waitcnt vmcnt(7)" ::: "memory");  // 7 = this wave's next-stage calls
    } else {
      asm volatile("s_waitcnt vmcnt(0)" ::: "memory");
    }
    __builtin_amdgcn_sched_barrier(0);
    __builtin_amdgcn_s_barrier();  // current tile fully in LDS

    // B fragments: gather 8 fp32 (klocal = lg*8+j), split bf16x3, pack
    short8v bh[2], bm[2], bl[2];
#pragma unroll
    for (int cf = 0; cf < 2; ++cf) {
      const char* zp = zbuf_b + cur * 16640 + lg * 4160 +
                       (w * 32 + cf * 16 + lrow) * 4;
      float x[8];
#pragma unroll
      for (int j = 0; j < 8; ++j)
        x[j] = *(const float*)(zp + (j >> 1) * 1040 + (j & 1) * 512);
      __align__(16) unsigned short h8[8], m8[8], l8[8];
#pragma unroll
      for (int j = 0; j < 8; ++j) {
        unsigned short h = f2bf_rne(x[j]);
        float r1 = x[j] - bf2f(h);
        unsigned short m = (unsigned short)(__float_as_uint(r1) >> 16);
        float r2 = r1 - bf2f(m);
        unsigned short lo = (unsigned short)(__float_as_uint(r2) >> 16);
        h8[j] = h; m8[j] = m; l8[j] = lo;
      }
      bh[cf] = *(const short8v*)h8;
      bm[cf] = *(const short8v*)m8;
      bl[cf] = *(const short8v*)l8;
    }
    // A fragments (3 splits x 4 rf)
    short8v ah[4], am[4], al[4];
#pragma unroll
    for (int rf = 0; rf < 4; ++rf) {
      int coff = (rf * 16 + lrow) * 64 + lg * 16;
      const char* ab = abuf_b + cur * 12288 + coff;
      ah[rf] = *(const short8v*)(ab);
      am[rf] = *(const short8v*)(ab + 4096);
      al[rf] = *(const short8v*)(ab + 8192);
    }
#pragma unroll
    for (int rf = 0; rf < 4; ++rf)
#pragma unroll
      for (int cf = 0; cf < 2; ++cf) {
        float4v a_ = acc[rf][cf];
        a_ = __builtin_amdgcn_mfma_f32_16x16x32_bf16(ah[rf], bh[cf], a_, 0, 0, 0);
        a_ = __builtin_amdgcn_mfma_f32_16x16x32_bf16(am[rf], bh[cf], a_, 0, 0, 0);
        a_ = __builtin_amdgcn_mfma_f32_16x16x32_bf16(ah[rf], bm[cf], a_, 0, 0, 0);
        a_ = __builtin_amdgcn_mfma_f32_16x16x32_bf16(am[rf], bm[cf], a_, 0, 0, 0);
        a_ = __builtin_amdgcn_mfma_f32_16x16x32_bf16(al[rf], bh[cf], a_, 0, 0, 0);
        a_ = __builtin_amdgcn_mfma_f32_16x16x32_bf16(ah[rf], bl[cf], a_, 0, 0, 0);
        acc[rf][cf] = a_;
      }
    __builtin_amdgcn_s_barrier();  // reads of cur done before restage
    cur ^= 1;
  }

  // epilogue: C layout col=lane&15 (t), row=(lane>>4)*4+reg (c)
  int tbase = t0 + w * 32;
#pragma unroll
  for (int rf = 0; rf < 4; ++rf) {
    float bv[4];
#pragma unroll
    for (int rg = 0; rg < 4; ++rg) bv[rg] = in_b[c0 + rf * 16 + lg * 4 + rg];
#pragma unroll
    for (int cf = 0; cf < 2; ++cf) {
      int t = tbase + cf * 16 + lrow;
#pragma unroll
      for (int rg = 0; rg < 4; ++rg) {
        int c = c0 + rf * 16 + lg * 4 + rg;
        out[OUT_ZE + (size_t)(b * CD_ + c) * T_ + t] = acc[rf][cf][rg] + bv[rg];
      }
      __align__(8) unsigned short us[4];
#pragma unroll
      for (int rg = 0; rg < 4; ++rg) us[rg] = f2bf_rne(acc[rf][cf][rg] + bv[rg]);
      *(uint2*)&zeN[(size_t)(b * T_ + t) * CD_ + c0 + rf * 16 + lg * 4] =
          *(uint2*)us;
    }
  }
}

// ---- K2: MFMA coarse scan, two-pass (R8 structure + counted vmcnt) ----
template <int COLLECT>
__global__ __launch_bounds__(256, 2) void vq_scan(
    const unsigned short* __restrict__ zeN, const unsigned short* __restrict__ cbb,
    const float* __restrict__ c2, float* __restrict__ bestq,
    int* __restrict__ cnt, int* __restrict__ cand) {
  __shared__ __align__(16) unsigned short smem[2][TILE_CODES * CD_];  // 2 x 32 KB
  int tid = threadIdx.x;
  int w = tid >> 6, l = tid & 63;
  int lrow = l & 15, lg = l >> 4;
  int rowbase = blockIdx.x * SCAN_ROWS + w * ROWS_PER_WAVE;
  int cq = blockIdx.y;
  int cbase0 = cq * CODES_PER_SPLIT;

  if (COLLECT == 0 && cq == 0)
    cnt[blockIdx.x * SCAN_ROWS + tid] = 0;

  short8v a[4][8];
#pragma unroll
  for (int rf = 0; rf < 4; ++rf)
#pragma unroll
    for (int ks = 0; ks < 8; ++ks)
      a[rf][ks] = *(const short8v*)&zeN[((size_t)(rowbase + rf * 16 + lrow)) * CD_ + ks * 32 + lg * 8];

  float best[16];
  float thr[16];
#pragma unroll
  for (int s = 0; s < 16; ++s) best[s] = -3.4e38f;
  if (COLLECT) {
#pragma unroll
    for (int s = 0; s < 16; ++s) {
      int rf = s >> 2, rg = s & 3;
      thr[s] = bestq[rowbase + rf * 16 + lg * 4 + rg];  // rowmax - DELTA
    }
  }

  int lhalf = l >> 5;
  int lcol = (l & 31) * 16;
  char* smem_b = (char*)&smem[0][0];
  const char* cbb_b = (const char*)cbb;
  int xsw = (lrow & 7) << 4;

  auto stage = [&](int buf, int cbase) {
#pragma unroll
    for (int r = 0; r < 8; ++r) {
      int code = w * 16 + r * 2 + lhalf;
      size_t goff = (size_t)(cbase + code) * 512 + (size_t)(lcol ^ ((code & 7) << 4));
      gload_lds16(cbb_b + goff, smem_b + buf * 32768 + (w * 8 + r) * 1024);
    }
  };

  stage(0, cbase0);

  for (int t = 0; t < NT_SPLIT; ++t) {
    int buf = t & 1;
    int cbase = cbase0 + t * TILE_CODES;

    float hc2[4];
#pragma unroll
    for (int cf = 0; cf < 4; ++cf) hc2[cf] = 0.5f * c2[cbase + cf * 16 + lrow];

    if (t + 1 < NT_SPLIT) {
      stage(buf ^ 1, cbase + TILE_CODES);
      asm volatile("s_waitcnt vmcnt(8)" ::: "memory");
    } else {
      asm volatile("s_waitcnt vmcnt(0)" ::: "memory");
    }
    __builtin_amdgcn_sched_barrier(0);
    __builtin_amdgcn_s_barrier();

    const char* bufb = smem_b + buf * 32768;
#pragma unroll
    for (int cf = 0; cf < 4; ++cf) {
      const char* bbase = bufb + (cf * 16 + lrow) * 512;
      float4v acc[4];
#pragma unroll
      for (int rf = 0; rf < 4; ++rf) acc[rf] = (float4v){0.f, 0.f, 0.f, 0.f};
#pragma unroll
      for (int ks = 0; ks < 8; ++ks) {
        short8v bfrag = *(const short8v*)(bbase + ((ks * 64 + lg * 16) ^ xsw));
        acc[0] = __builtin_amdgcn_mfma_f32_16x16x32_bf16(a[0][ks], bfrag, acc[0], 0, 0, 0);
        acc[1] = __builtin_amdgcn_mfma_f32_16x16x32_bf16(a[1][ks], bfrag, acc[1], 0, 0, 0);
        acc[2] = __builtin_amdgcn_mfma_f32_16x16x32_bf16(a[2][ks], bfrag, acc[2], 0, 0, 0);
        acc[3] = __builtin_amdgcn_mfma_f32_16x16x32_bf16(a[3][ks], bfrag, acc[3], 0, 0, 0);
      }
      int ci = cbase + cf * 16 + lrow;
#pragma unroll
      for (int rf = 0; rf < 4; ++rf)
#pragma unroll
        for (int rg = 0; rg < 4; ++rg) {
          float sc = acc[rf][rg] - hc2[cf];
          int slot = rf * 4 + rg;
          if (COLLECT) {
            if (sc >= thr[slot]) {
              int row = rowbase + rf * 16 + lg * 4 + rg;
              int pos = atomicAdd(&cnt[row], 1);
              if (pos < 16) cand[row * 16 + pos] = ci;
            }
          } else {
            best[slot] = fmaxf(best[slot], sc);
          }
        }
    }
    __builtin_amdgcn_s_barrier();
  }

  if (!COLLECT) {
#pragma unroll
    for (int s = 0; s < 16; ++s) {
      float v = best[s];
#pragma unroll
      for (int off = 1; off < 16; off <<= 1) v = fmaxf(v, __shfl_xor(v, off));
      best[s] = v;
    }
    if (lrow == 0) {
#pragma unroll
      for (int s = 0; s < 16; ++s) {
        int rf = s >> 2, rg = s & 3;
        bestq[cq * N_ + rowbase + rf * 16 + lg * 4 + rg] = best[s];
      }
    }
  }
}

// ---- fold split maxima into per-row threshold, in place (row 0 of bestq) ----
__global__ __launch_bounds__(256) void vq_rowthr(float* __restrict__ bestq) {
  int n = blockIdx.x * 256 + threadIdx.x;
  float m = bestq[n];
#pragma unroll
  for (int q = 1; q < NSPLIT; ++q) m = fmaxf(m, bestq[q * N_ + n]);
  bestq[n] = m - DELTA;
}

// ---- exact fp32 rescore of candidates; lexicographic (dist, idx) min ----
__global__ __launch_bounds__(256) void vq_rescore(
    const float* __restrict__ ze, const float* __restrict__ cb,
    const int* __restrict__ cnt, const int* __restrict__ cand,
    float* __restrict__ out, int* __restrict__ idx_ws) {
  int tid = threadIdx.x;
  int n = blockIdx.x * 64 + (tid >> 2);
  int j = tid & 3;
  int b = n >> 11, t = n & (T_ - 1);
  const float* zr = ze + ((size_t)b * CD_) * T_ + t;  // element k at zr[k*T_]
  int m = cnt[n]; if (m > 16) m = 16;
  float bd = 3.4e38f; int bi = 0x7fffffff;
  for (int i = 0; i < m; ++i) {
    int c = cand[n * 16 + i];
    const float* cr = cb + (size_t)c * CD_;
    float d = 0.f;
    for (int k = j; k < CD_; k += 4) {
      float diff = zr[(size_t)k * T_] - cr[k];
      d = fmaf(diff, diff, d);
    }
    d += __shfl_xor(d, 1);
    d += __shfl_xor(d, 2);
    if (d < bd || (d == bd && c < bi)) { bd = d; bi = c; }
  }
  if (j == 0) {
    idx_ws[n] = bi;
    out[OUT_IDX + n] = (float)bi;
  }
}

// ---- K3 (MFMA): z_q = w_out @ codebook[idx] + out_b ----
__global__ __launch_bounds__(256, 2) void zq_mfma(
    const unsigned short* __restrict__ wob, const unsigned short* __restrict__ cbb,
    const float* __restrict__ out_bias, const int* __restrict__ idx,
    float* __restrict__ out) {
  __shared__ __align__(16) unsigned short Bs[64 * CD_];  // 32 KB
  __shared__ int idxs[64];
  int tid = threadIdx.x;
  int w = tid >> 6, l = tid & 63;
  int lrow = l & 15, lg = l >> 4;
  int t0 = blockIdx.x * 64, d0 = blockIdx.y * 256, b = blockIdx.z;
  int rowbase = d0 + w * 64;

  if (tid < 64) idxs[tid] = idx[b * T_ + t0 + tid];

  short8v a[4][8];
#pragma unroll
  for (int rf = 0; rf < 4; ++rf)
#pragma unroll
    for (int ks = 0; ks < 8; ++ks)
      a[rf][ks] = *(const short8v*)&wob[((size_t)(rowbase + rf * 16 + lrow)) * CD_ + ks * 32 + lg * 8];

  __syncthreads();  // idxs ready

  int lhalf = l >> 5;
  int lcol = (l & 31) * 16;
  char* Bs_b = (char*)&Bs[0];
  const char* cbb_b = (const char*)cbb;
#pragma unroll
  for (int r = 0; r < 8; ++r) {
    int t = w * 16 + r * 2 + lhalf;
    int row = idxs[t];
    size_t goff = (size_t)row * 512 + (size_t)(lcol ^ ((t & 7) << 4));
    gload_lds16(cbb_b + goff, Bs_b + (w * 8 + r) * 1024);
  }
  __syncthreads();  // drains vmcnt

  int xsw = (lrow & 7) << 4;
  float4v acc[4][4];
#pragma unroll
  for (int rf = 0; rf < 4; ++rf)
#pragma unroll
    for (int cf = 0; cf < 4; ++cf) acc[rf][cf] = (float4v){0.f, 0.f, 0.f, 0.f};
#pragma unroll
  for (int cf = 0; cf < 4; ++cf) {
    const char* bbase = Bs_b + (cf * 16 + lrow) * 512;
#pragma unroll
    for (int ks = 0; ks < 8; ++ks) {
      short8v bfrag = *(const short8v*)(bbase + ((ks * 64 + lg * 16) ^ xsw));
      acc[0][cf] = __builtin_amdgcn_mfma_f32_16x16x32_bf16(a[0][ks], bfrag, acc[0][cf], 0, 0, 0);
      acc[1][cf] = __builtin_amdgcn_mfma_f32_16x16x32_bf16(a[1][ks], bfrag, acc[1][cf], 0, 0, 0);
      acc[2][cf] = __builtin_amdgcn_mfma_f32_16x16x32_bf16(a[2][ks], bfrag, acc[2][cf], 0, 0, 0);
      acc[3][cf] = __builtin_amdgcn_mfma_f32_16x16x32_bf16(a[3][ks], bfrag, acc[3][cf], 0, 0, 0);
    }
  }
#pragma unroll
  for (int rf = 0; rf < 4; ++rf) {
    float bias[4];
#pragma unroll
    for (int rg = 0; rg < 4; ++rg) bias[rg] = out_bias[rowbase + rf * 16 + lg * 4 + rg];
#pragma unroll
    for (int cf = 0; cf < 4; ++cf) {
      int t = t0 + cf * 16 + lrow;
#pragma unroll
      for (int rg = 0; rg < 4; ++rg) {
        int d = rowbase + rf * 16 + lg * 4 + rg;
        out[OUT_ZQ + (size_t)(b * D_ + d) * T_ + t] = acc[rf][cf][rg] + bias[rg];
      }
    }
  }
}

extern "C" void kernel_launch(void* const* d_in, const int* in_sizes, int n_in,
                              void* d_out, int out_size, void* d_ws,
                              size_t ws_size, hipStream_t stream) {
  const float* z     = (const float*)d_in[0];
  const float* in_v  = (const float*)d_in[1];
  const float* in_g  = (const float*)d_in[2];
  const float* in_b  = (const float*)d_in[3];
  const float* out_v = (const float*)d_in[4];
  const float* out_g = (const float*)d_in[5];
  const float* out_b = (const float*)d_in[6];
  const float* cb    = (const float*)d_in[7];
  float* out = (float*)d_out;
  float* ws  = (float*)d_ws;

  unsigned short* zeN = (unsigned short*)(ws + WS_ZEN);
  unsigned short* cbb = (unsigned short*)(ws + WS_CBB);
  unsigned short* wh  = (unsigned short*)(ws + WS_WH);
  unsigned short* wm  = (unsigned short*)(ws + WS_WM);
  unsigned short* wl  = (unsigned short*)(ws + WS_WL);
  unsigned short* wob = (unsigned short*)(ws + WS_WOB);
  float* c2     = ws + WS_C2;
  int*   cnt    = (int*)(ws + WS_CNT);
  int*   cand   = (int*)(ws + WS_CAND);
  int*   idxw   = (int*)(ws + WS_IDX);
  // bestq scratch lives in d_out's z_q region (overwritten later by zq_mfma)
  float* bestq  = out + OUT_ZQ;

  prep_all<<<CD_ + D_ + CS_ / 4 + CS_ * CD_ / 8 / 256, 256, 0, stream>>>(
      in_v, in_g, out_v, out_g, cb, wh, wm, wl, wob, c2, cbb);

  ze_mfma<<<dim3(T_ / 128, CD_ / 64, B_), 256, 0, stream>>>(
      z, wh, wm, wl, in_b, out, zeN);

  vq_scan<0><<<dim3(N_ / SCAN_ROWS, NSPLIT), 256, 0, stream>>>(
      zeN, cbb, c2, bestq, cnt, cand);
  vq_rowthr<<<N_ / 256, 256, 0, stream>>>(bestq);
  vq_scan<1><<<dim3(N_ / SCAN_ROWS, NSPLIT), 256, 0, stream>>>(
      zeN, cbb, c2, bestq, cnt, cand);
  vq_rescore<<<N_ / 64, 256, 0, stream>>>(out + OUT_ZE, cb, cnt, cand, out, idxw);

  zq_mfma<<<dim3(T_ / 64, D_ / 256, B_), 256, 0, stream>>>(wob, cbb, out_b, idxw, out);
}

// Round 14
// 313.408 us; speedup vs baseline: 2.4078x; 1.0461x over previous
//
#include <hip/hip_runtime.h>
#include <math.h>

// Problem constants
#define B_  8
#define D_  1024
#define T_  2048
#define CD_ 256
#define CS_ 8192
#define N_  (B_*T_)

#define NSPLIT 8
#define CODES_PER_SPLIT (CS_/NSPLIT)   // 1024
#define NT_SPLIT (CODES_PER_SPLIT/64)  // 16 tiles per split
#define DELTA 1.5f                     // score-units; >> 2*bf16 dot error

// scan geometry: 4 waves * 64 rows = 256 rows/block; 64-code LDS tiles
#define ROWS_PER_WAVE 64
#define SCAN_ROWS 256
#define TILE_CODES 64

// ws layout (float offsets). bestq lives in d_out's z_q region.
#define WS_ZEN   0                        // bf16 [N][256]   (2,097,152 float slots)
#define WS_CBB   2097152                  // bf16 [CS][256]  (1,048,576)
#define WS_WH    (WS_CBB + 1048576)       // bf16 [CD][D] hi   (131072)
#define WS_WM    (WS_WH + 131072)         // bf16 [CD][D] mid
#define WS_WOB   (WS_WM + 131072)         // bf16 [D][CD]
#define WS_C2    (WS_WOB + 131072)        // f32 [CS]
#define WS_CNT   (WS_C2 + CS_)            // int [N]
#define WS_CAND  (WS_CNT + N_)            // int [N][16]
#define WS_IDX   (WS_CAND + N_*16)        // int [N]

// d_out layout (floats): z_q, indices(as float), z_e
#define OUT_ZQ  0
#define OUT_IDX (B_*D_*T_)
#define OUT_ZE  (OUT_IDX + B_*T_)

using short8v = __attribute__((ext_vector_type(8))) short;
using float4v = __attribute__((ext_vector_type(4))) float;

__device__ __forceinline__ float wave_sum64(float v) {
#pragma unroll
  for (int off = 32; off >= 1; off >>= 1) v += __shfl_xor(v, off);
  return v;
}

__device__ __forceinline__ unsigned short f2bf_rne(float f) {
  unsigned int u = __float_as_uint(f);
  u += 0x7fffu + ((u >> 16) & 1u);
  return (unsigned short)(u >> 16);
}

__device__ __forceinline__ float bf2f(unsigned short u) {
  return __uint_as_float(((unsigned)u) << 16);
}

__device__ __forceinline__ void gload_lds16(const void* g, void* l) {
  __builtin_amdgcn_global_load_lds(
      (const __attribute__((address_space(1))) void*)g,
      (__attribute__((address_space(3))) void*)l, 16, 0, 0);
}

// ---- fused prep: one kernel, block-range dispatch ----
// [0,256): w_in splits (bf16x2)  [256,1280): wob  [1280,2304): cbb + c2 fused
__global__ __launch_bounds__(256) void prep_all(
    const float* __restrict__ in_v, const float* __restrict__ in_g,
    const float* __restrict__ out_v, const float* __restrict__ out_g,
    const float* __restrict__ cb,
    unsigned short* __restrict__ wh, unsigned short* __restrict__ wm,
    unsigned short* __restrict__ wob,
    float* __restrict__ c2, unsigned short* __restrict__ cbb) {
  __shared__ float sh[4];
  int blk = blockIdx.x, tid = threadIdx.x;
  if (blk < CD_) {
    // w row c = in_g[c]*in_v[c,:]/||.|| (exact fp32), split bf16 hi+mid
    int c = blk;
    float v[4]; float s = 0.f;
#pragma unroll
    for (int i = 0; i < 4; ++i) {
      v[i] = in_v[c * D_ + tid + 256 * i];
      s = fmaf(v[i], v[i], s);
    }
    s = wave_sum64(s);
    if ((tid & 63) == 0) sh[tid >> 6] = s;
    __syncthreads();
    float tot = sh[0] + sh[1] + sh[2] + sh[3];
    float scale = in_g[c] / sqrtf(tot);
#pragma unroll
    for (int i = 0; i < 4; ++i) {
      int d = tid + 256 * i;
      float x = v[i] * scale;
      unsigned short h = f2bf_rne(x);
      float r1 = x - bf2f(h);
      unsigned short m = (unsigned short)(__float_as_uint(r1) >> 16);
      wh[c * D_ + d] = h; wm[c * D_ + d] = m;
    }
  } else if (blk < CD_ + D_) {
    int d = blk - CD_;
    float v = out_v[d * CD_ + tid];
    float s = wave_sum64(v * v);
    if ((tid & 63) == 0) sh[tid >> 6] = s;
    __syncthreads();
    float tot = sh[0] + sh[1] + sh[2] + sh[3];
    float scale = out_g[d] / sqrtf(tot);
    wob[d * CD_ + tid] = f2bf_rne(v * scale);
  } else {
    // cbb convert + fused c2: block covers 8 cb rows; 32 threads per row.
    size_t i = (size_t)(blk - CD_ - D_) * 256 + tid;  // octet index
    float4 v0 = *(const float4*)&cb[i * 8];
    float4 v1 = *(const float4*)&cb[i * 8 + 4];
    float f[8] = {v0.x, v0.y, v0.z, v0.w, v1.x, v1.y, v1.z, v1.w};
    unsigned short us[8];
    float sq = 0.f;
#pragma unroll
    for (int m = 0; m < 8; ++m) {
      us[m] = f2bf_rne(f[m]);
      sq = fmaf(f[m], f[m], sq);
    }
    *(uint4*)&cbb[i * 8] = *(uint4*)&us[0];
#pragma unroll
    for (int off = 1; off < 32; off <<= 1) sq += __shfl_xor(sq, off);
    if ((tid & 31) == 0) c2[i >> 5] = sq;
  }
}

// ---- K1 (MFMA, bf16x2 split, 4-term): z_e = w_in @ z + b ----
// tile 64c x 128t, 256 thr, 4 waves (wave w owns t-range w*32..+32; rf=4 c,
// cf=2 t). K streamed BK=32, double-buffered. A = precomputed w-splits
// ([c][d] k-contig). B = z staged fp32 with 1040-B pair-stride pad, split to
// bf16 hi+mid in-register. 4-term product (hh,mh,hm,mm): dropped residual
// terms ~2^-17|wz| -> z_e error ~4e-6, far below the ~1e-5 fp32
// accumulation-order noise this pipeline already tolerates (R13 passed).
__global__ __launch_bounds__(256, 2) void ze_mfma(
    const float* __restrict__ z,
    const unsigned short* __restrict__ whp, const unsigned short* __restrict__ wmp,
    const float* __restrict__ in_b,
    float* __restrict__ out, unsigned short* __restrict__ zeN) {
  __shared__ __align__(16) char zbuf[2][16 * 1040];          // 2 x 16640 B
  __shared__ __align__(16) unsigned short abuf[2][2][2048];  // 2 x 8 KB
  int tid = threadIdx.x;
  int w = tid >> 6, l = tid & 63;
  int lrow = l & 15, lg = l >> 4;
  int t0 = blockIdx.x * 128, c0 = blockIdx.y * 64, b = blockIdx.z;
  const float* zb = z + (size_t)b * D_ * T_;
  char* zbuf_b = &zbuf[0][0];
  char* abuf_b = (char*)&abuf[0][0][0];

  auto stage = [&](int buf, int kc) {
    // z: 16 pair-calls (pair g = rows 2g,2g+1); wave w does g = 4w..4w+3
#pragma unroll
    for (int i = 0; i < 4; ++i) {
      int g = w * 4 + i;
      int row = 2 * g + (l >> 5);
      gload_lds16(&zb[(size_t)(kc + row) * T_ + t0 + (l & 31) * 4],
                  zbuf_b + buf * 16640 + g * 1040);
    }
    // A: 2 splits x 4 calls (16 c-rows each); wave w does call w per split
    int c = w * 16 + (l >> 2);
    int doff = (l & 3) * 8;
    gload_lds16(&whp[(size_t)(c0 + c) * D_ + kc + doff],
                abuf_b + buf * 8192 + w * 1024);
    gload_lds16(&wmp[(size_t)(c0 + c) * D_ + kc + doff],
                abuf_b + buf * 8192 + 4096 + w * 1024);
  };

  float4v acc[4][2];
#pragma unroll
  for (int rf = 0; rf < 4; ++rf)
#pragma unroll
    for (int cf = 0; cf < 2; ++cf) acc[rf][cf] = (float4v){0.f, 0.f, 0.f, 0.f};

  stage(0, 0);
  int cur = 0;
  for (int kt = 0; kt < D_ / 32; ++kt) {
    if (kt + 1 < D_ / 32) {
      stage(cur ^ 1, (kt + 1) * 32);
      asm volatile("s_waitcnt vmcnt(6)" ::: "memory");  // 6 = next-stage calls
    } else {
      asm volatile("s_waitcnt vmcnt(0)" ::: "memory");
    }
    __builtin_amdgcn_sched_barrier(0);
    __builtin_amdgcn_s_barrier();  // current tile fully in LDS

    // B fragments: gather 8 fp32 (klocal = lg*8+j), split bf16 hi+mid, pack
    short8v bh[2], bm[2];
#pragma unroll
    for (int cf = 0; cf < 2; ++cf) {
      const char* zp = zbuf_b + cur * 16640 + lg * 4160 +
                       (w * 32 + cf * 16 + lrow) * 4;
      float x[8];
#pragma unroll
      for (int j = 0; j < 8; ++j)
        x[j] = *(const float*)(zp + (j >> 1) * 1040 + (j & 1) * 512);
      __align__(16) unsigned short h8[8], m8[8];
#pragma unroll
      for (int j = 0; j < 8; ++j) {
        unsigned short h = f2bf_rne(x[j]);
        float r1 = x[j] - bf2f(h);
        m8[j] = (unsigned short)(__float_as_uint(r1) >> 16);
        h8[j] = h;
      }
      bh[cf] = *(const short8v*)h8;
      bm[cf] = *(const short8v*)m8;
    }
    // A fragments (2 splits x 4 rf)
    short8v ah[4], am[4];
#pragma unroll
    for (int rf = 0; rf < 4; ++rf) {
      int coff = (rf * 16 + lrow) * 64 + lg * 16;
      const char* ab = abuf_b + cur * 8192 + coff;
      ah[rf] = *(const short8v*)(ab);
      am[rf] = *(const short8v*)(ab + 4096);
    }
#pragma unroll
    for (int rf = 0; rf < 4; ++rf)
#pragma unroll
      for (int cf = 0; cf < 2; ++cf) {
        float4v a_ = acc[rf][cf];
        a_ = __builtin_amdgcn_mfma_f32_16x16x32_bf16(ah[rf], bh[cf], a_, 0, 0, 0);
        a_ = __builtin_amdgcn_mfma_f32_16x16x32_bf16(am[rf], bh[cf], a_, 0, 0, 0);
        a_ = __builtin_amdgcn_mfma_f32_16x16x32_bf16(ah[rf], bm[cf], a_, 0, 0, 0);
        a_ = __builtin_amdgcn_mfma_f32_16x16x32_bf16(am[rf], bm[cf], a_, 0, 0, 0);
        acc[rf][cf] = a_;
      }
    __builtin_amdgcn_s_barrier();  // reads of cur done before restage
    cur ^= 1;
  }

  // epilogue: C layout col=lane&15 (t), row=(lane>>4)*4+reg (c)
  int tbase = t0 + w * 32;
#pragma unroll
  for (int rf = 0; rf < 4; ++rf) {
    float bv[4];
#pragma unroll
    for (int rg = 0; rg < 4; ++rg) bv[rg] = in_b[c0 + rf * 16 + lg * 4 + rg];
#pragma unroll
    for (int cf = 0; cf < 2; ++cf) {
      int t = tbase + cf * 16 + lrow;
#pragma unroll
      for (int rg = 0; rg < 4; ++rg) {
        int c = c0 + rf * 16 + lg * 4 + rg;
        out[OUT_ZE + (size_t)(b * CD_ + c) * T_ + t] = acc[rf][cf][rg] + bv[rg];
      }
      __align__(8) unsigned short us[4];
#pragma unroll
      for (int rg = 0; rg < 4; ++rg) us[rg] = f2bf_rne(acc[rf][cf][rg] + bv[rg]);
      *(uint2*)&zeN[(size_t)(b * T_ + t) * CD_ + c0 + rf * 16 + lg * 4] =
          *(uint2*)us;
    }
  }
}

// ---- K2: MFMA coarse scan, two-pass (R8 structure + counted vmcnt) ----
template <int COLLECT>
__global__ __launch_bounds__(256, 2) void vq_scan(
    const unsigned short* __restrict__ zeN, const unsigned short* __restrict__ cbb,
    const float* __restrict__ c2, float* __restrict__ bestq,
    int* __restrict__ cnt, int* __restrict__ cand) {
  __shared__ __align__(16) unsigned short smem[2][TILE_CODES * CD_];  // 2 x 32 KB
  int tid = threadIdx.x;
  int w = tid >> 6, l = tid & 63;
  int lrow = l & 15, lg = l >> 4;
  int rowbase = blockIdx.x * SCAN_ROWS + w * ROWS_PER_WAVE;
  int cq = blockIdx.y;
  int cbase0 = cq * CODES_PER_SPLIT;

  if (COLLECT == 0 && cq == 0)
    cnt[blockIdx.x * SCAN_ROWS + tid] = 0;

  short8v a[4][8];
#pragma unroll
  for (int rf = 0; rf < 4; ++rf)
#pragma unroll
    for (int ks = 0; ks < 8; ++ks)
      a[rf][ks] = *(const short8v*)&zeN[((size_t)(rowbase + rf * 16 + lrow)) * CD_ + ks * 32 + lg * 8];

  float best[16];
  float thr[16];
#pragma unroll
  for (int s = 0; s < 16; ++s) best[s] = -3.4e38f;
  if (COLLECT) {
#pragma unroll
    for (int s = 0; s < 16; ++s) {
      int rf = s >> 2, rg = s & 3;
      thr[s] = bestq[rowbase + rf * 16 + lg * 4 + rg];  // rowmax - DELTA
    }
  }

  int lhalf = l >> 5;
  int lcol = (l & 31) * 16;
  char* smem_b = (char*)&smem[0][0];
  const char* cbb_b = (const char*)cbb;
  int xsw = (lrow & 7) << 4;

  auto stage = [&](int buf, int cbase) {
#pragma unroll
    for (int r = 0; r < 8; ++r) {
      int code = w * 16 + r * 2 + lhalf;
      size_t goff = (size_t)(cbase + code) * 512 + (size_t)(lcol ^ ((code & 7) << 4));
      gload_lds16(cbb_b + goff, smem_b + buf * 32768 + (w * 8 + r) * 1024);
    }
  };

  stage(0, cbase0);

  for (int t = 0; t < NT_SPLIT; ++t) {
    int buf = t & 1;
    int cbase = cbase0 + t * TILE_CODES;

    float hc2[4];
#pragma unroll
    for (int cf = 0; cf < 4; ++cf) hc2[cf] = 0.5f * c2[cbase + cf * 16 + lrow];

    if (t + 1 < NT_SPLIT) {
      stage(buf ^ 1, cbase + TILE_CODES);
      asm volatile("s_waitcnt vmcnt(8)" ::: "memory");
    } else {
      asm volatile("s_waitcnt vmcnt(0)" ::: "memory");
    }
    __builtin_amdgcn_sched_barrier(0);
    __builtin_amdgcn_s_barrier();

    const char* bufb = smem_b + buf * 32768;
#pragma unroll
    for (int cf = 0; cf < 4; ++cf) {
      const char* bbase = bufb + (cf * 16 + lrow) * 512;
      float4v acc[4];
#pragma unroll
      for (int rf = 0; rf < 4; ++rf) acc[rf] = (float4v){0.f, 0.f, 0.f, 0.f};
#pragma unroll
      for (int ks = 0; ks < 8; ++ks) {
        short8v bfrag = *(const short8v*)(bbase + ((ks * 64 + lg * 16) ^ xsw));
        acc[0] = __builtin_amdgcn_mfma_f32_16x16x32_bf16(a[0][ks], bfrag, acc[0], 0, 0, 0);
        acc[1] = __builtin_amdgcn_mfma_f32_16x16x32_bf16(a[1][ks], bfrag, acc[1], 0, 0, 0);
        acc[2] = __builtin_amdgcn_mfma_f32_16x16x32_bf16(a[2][ks], bfrag, acc[2], 0, 0, 0);
        acc[3] = __builtin_amdgcn_mfma_f32_16x16x32_bf16(a[3][ks], bfrag, acc[3], 0, 0, 0);
      }
      int ci = cbase + cf * 16 + lrow;
#pragma unroll
      for (int rf = 0; rf < 4; ++rf)
#pragma unroll
        for (int rg = 0; rg < 4; ++rg) {
          float sc = acc[rf][rg] - hc2[cf];
          int slot = rf * 4 + rg;
          if (COLLECT) {
            if (sc >= thr[slot]) {
              int row = rowbase + rf * 16 + lg * 4 + rg;
              int pos = atomicAdd(&cnt[row], 1);
              if (pos < 16) cand[row * 16 + pos] = ci;
            }
          } else {
            best[slot] = fmaxf(best[slot], sc);
          }
        }
    }
    __builtin_amdgcn_s_barrier();
  }

  if (!COLLECT) {
#pragma unroll
    for (int s = 0; s < 16; ++s) {
      float v = best[s];
#pragma unroll
      for (int off = 1; off < 16; off <<= 1) v = fmaxf(v, __shfl_xor(v, off));
      best[s] = v;
    }
    if (lrow == 0) {
#pragma unroll
      for (int s = 0; s < 16; ++s) {
        int rf = s >> 2, rg = s & 3;
        bestq[cq * N_ + rowbase + rf * 16 + lg * 4 + rg] = best[s];
      }
    }
  }
}

// ---- fold split maxima into per-row threshold, in place (row 0 of bestq) ----
__global__ __launch_bounds__(256) void vq_rowthr(float* __restrict__ bestq) {
  int n = blockIdx.x * 256 + threadIdx.x;
  float m = bestq[n];
#pragma unroll
  for (int q = 1; q < NSPLIT; ++q) m = fmaxf(m, bestq[q * N_ + n]);
  bestq[n] = m - DELTA;
}

// ---- exact fp32 rescore of candidates; lexicographic (dist, idx) min ----
__global__ __launch_bounds__(256) void vq_rescore(
    const float* __restrict__ ze, const float* __restrict__ cb,
    const int* __restrict__ cnt, const int* __restrict__ cand,
    float* __restrict__ out, int* __restrict__ idx_ws) {
  int tid = threadIdx.x;
  int n = blockIdx.x * 64 + (tid >> 2);
  int j = tid & 3;
  int b = n >> 11, t = n & (T_ - 1);
  const float* zr = ze + ((size_t)b * CD_) * T_ + t;  // element k at zr[k*T_]
  int m = cnt[n]; if (m > 16) m = 16;
  float bd = 3.4e38f; int bi = 0x7fffffff;
  for (int i = 0; i < m; ++i) {
    int c = cand[n * 16 + i];
    const float* cr = cb + (size_t)c * CD_;
    float d = 0.f;
    for (int k = j; k < CD_; k += 4) {
      float diff = zr[(size_t)k * T_] - cr[k];
      d = fmaf(diff, diff, d);
    }
    d += __shfl_xor(d, 1);
    d += __shfl_xor(d, 2);
    if (d < bd || (d == bd && c < bi)) { bd = d; bi = c; }
  }
  if (j == 0) {
    idx_ws[n] = bi;
    out[OUT_IDX + n] = (float)bi;
  }
}

// ---- K3 (MFMA): z_q = w_out @ codebook[idx] + out_b ----
__global__ __launch_bounds__(256, 2) void zq_mfma(
    const unsigned short* __restrict__ wob, const unsigned short* __restrict__ cbb,
    const float* __restrict__ out_bias, const int* __restrict__ idx,
    float* __restrict__ out) {
  __shared__ __align__(16) unsigned short Bs[64 * CD_];  // 32 KB
  __shared__ int idxs[64];
  int tid = threadIdx.x;
  int w = tid >> 6, l = tid & 63;
  int lrow = l & 15, lg = l >> 4;
  int t0 = blockIdx.x * 64, d0 = blockIdx.y * 256, b = blockIdx.z;
  int rowbase = d0 + w * 64;

  if (tid < 64) idxs[tid] = idx[b * T_ + t0 + tid];

  short8v a[4][8];
#pragma unroll
  for (int rf = 0; rf < 4; ++rf)
#pragma unroll
    for (int ks = 0; ks < 8; ++ks)
      a[rf][ks] = *(const short8v*)&wob[((size_t)(rowbase + rf * 16 + lrow)) * CD_ + ks * 32 + lg * 8];

  __syncthreads();  // idxs ready

  int lhalf = l >> 5;
  int lcol = (l & 31) * 16;
  char* Bs_b = (char*)&Bs[0];
  const char* cbb_b = (const char*)cbb;
#pragma unroll
  for (int r = 0; r < 8; ++r) {
    int t = w * 16 + r * 2 + lhalf;
    int row = idxs[t];
    size_t goff = (size_t)row * 512 + (size_t)(lcol ^ ((t & 7) << 4));
    gload_lds16(cbb_b + goff, Bs_b + (w * 8 + r) * 1024);
  }
  __syncthreads();  // drains vmcnt

  int xsw = (lrow & 7) << 4;
  float4v acc[4][4];
#pragma unroll
  for (int rf = 0; rf < 4; ++rf)
#pragma unroll
    for (int cf = 0; cf < 4; ++cf) acc[rf][cf] = (float4v){0.f, 0.f, 0.f, 0.f};
#pragma unroll
  for (int cf = 0; cf < 4; ++cf) {
    const char* bbase = Bs_b + (cf * 16 + lrow) * 512;
#pragma unroll
    for (int ks = 0; ks < 8; ++ks) {
      short8v bfrag = *(const short8v*)(bbase + ((ks * 64 + lg * 16) ^ xsw));
      acc[0][cf] = __builtin_amdgcn_mfma_f32_16x16x32_bf16(a[0][ks], bfrag, acc[0][cf], 0, 0, 0);
      acc[1][cf] = __builtin_amdgcn_mfma_f32_16x16x32_bf16(a[1][ks], bfrag, acc[1][cf], 0, 0, 0);
      acc[2][cf] = __builtin_amdgcn_mfma_f32_16x16x32_bf16(a[2][ks], bfrag, acc[2][cf], 0, 0, 0);
      acc[3][cf] = __builtin_amdgcn_mfma_f32_16x16x32_bf16(a[3][ks], bfrag, acc[3][cf], 0, 0, 0);
    }
  }
#pragma unroll
  for (int rf = 0; rf < 4; ++rf) {
    float bias[4];
#pragma unroll
    for (int rg = 0; rg < 4; ++rg) bias[rg] = out_bias[rowbase + rf * 16 + lg * 4 + rg];
#pragma unroll
    for (int cf = 0; cf < 4; ++cf) {
      int t = t0 + cf * 16 + lrow;
#pragma unroll
      for (int rg = 0; rg < 4; ++rg) {
        int d = rowbase + rf * 16 + lg * 4 + rg;
        out[OUT_ZQ + (size_t)(b * D_ + d) * T_ + t] = acc[rf][cf][rg] + bias[rg];
      }
    }
  }
}

extern "C" void kernel_launch(void* const* d_in, const int* in_sizes, int n_in,
                              void* d_out, int out_size, void* d_ws,
                              size_t ws_size, hipStream_t stream) {
  const float* z     = (const float*)d_in[0];
  const float* in_v  = (const float*)d_in[1];
  const float* in_g  = (const float*)d_in[2];
  const float* in_b  = (const float*)d_in[3];
  const float* out_v = (const float*)d_in[4];
  const float* out_g = (const float*)d_in[5];
  const float* out_b = (const float*)d_in[6];
  const float* cb    = (const float*)d_in[7];
  float* out = (float*)d_out;
  float* ws  = (float*)d_ws;

  unsigned short* zeN = (unsigned short*)(ws + WS_ZEN);
  unsigned short* cbb = (unsigned short*)(ws + WS_CBB);
  unsigned short* wh  = (unsigned short*)(ws + WS_WH);
  unsigned short* wm  = (unsigned short*)(ws + WS_WM);
  unsigned short* wob = (unsigned short*)(ws + WS_WOB);
  float* c2     = ws + WS_C2;
  int*   cnt    = (int*)(ws + WS_CNT);
  int*   cand   = (int*)(ws + WS_CAND);
  int*   idxw   = (int*)(ws + WS_IDX);
  // bestq scratch lives in d_out's z_q region (overwritten later by zq_mfma)
  float* bestq  = out + OUT_ZQ;

  prep_all<<<CD_ + D_ + CS_ * CD_ / 8 / 256, 256, 0, stream>>>(
      in_v, in_g, out_v, out_g, cb, wh, wm, wob, c2, cbb);

  ze_mfma<<<dim3(T_ / 128, CD_ / 64, B_), 256, 0, stream>>>(
      z, wh, wm, in_b, out, zeN);

  vq_scan<0><<<dim3(N_ / SCAN_ROWS, NSPLIT), 256, 0, stream>>>(
      zeN, cbb, c2, bestq, cnt, cand);
  vq_rowthr<<<N_ / 256, 256, 0, stream>>>(bestq);
  vq_scan<1><<<dim3(N_ / SCAN_ROWS, NSPLIT), 256, 0, stream>>>(
      zeN, cbb, c2, bestq, cnt, cand);
  vq_rescore<<<N_ / 64, 256, 0, stream>>>(out + OUT_ZE, cb, cnt, cand, out, idxw);

  zq_mfma<<<dim3(T_ / 64, D_ / 256, B_), 256, 0, stream>>>(wob, cbb, out_b, idxw, out);
}